// Round 9
// baseline (472.945 us; speedup 1.0000x reference)
//
#include <hip/hip_runtime.h>
#include <math.h>

// ---- static config (mirrors reference) ----
constexpr int BB  = 32;     // batch
constexpr int MM  = 20;     // max gt per image
constexpr int NCC = 80;     // classes
constexpr int RM  = 16;     // reg_max
constexpr int NOC = 144;    // channels per head
constexpr int AT  = 8400;   // anchors
constexpr int TK  = 10;     // topk
constexpr int BA  = BB * AT;  // 268800
constexpr int BM  = BB * MM;  // 640
constexpr int MAXPOS = BM * TK; // 6400 topk entries
constexpr int NSLOT = 1024;     // max candidates per gt
constexpr float EPS_A = 1e-9f;
constexpr float VCOEF = 0.40528473456935108577551785283891f; // 4/pi^2

// fused feature pass: one block per (image, tile). Tiles per image:
// lvl0: 25x256 ; lvl1: 6x256 + 1x64 ; lvl2: 1x256 + 1x144  -> 34 tiles
constexpr int TPI    = 34;
constexpr int NTILES = BB * TPI;   // 1088

struct Lvl { const float* f; int o, w, hw; float s; };

__device__ inline Lvl level_of(int a, const float* f0, const float* f1, const float* f2){
  Lvl L;
  if (a < 6400)      { L.f = f0; L.o = a;        L.w = 80; L.hw = 6400; L.s = 8.f;  }
  else if (a < 8000) { L.f = f1; L.o = a - 6400; L.w = 40; L.hw = 1600; L.s = 16.f; }
  else               { L.f = f2; L.o = a - 8000; L.w = 20; L.hw = 400;  L.s = 32.f; }
  return L;
}

__device__ inline float frcp(float x){ return __builtin_amdgcn_rcpf(x); }

// fast atan, |err| < ~2e-6
__device__ inline float fast_atan(float x){
  float ax = fabsf(x);
  bool big = ax > 1.f;
  float z = big ? frcp(ax) : ax;
  float z2 = z * z;
  float p = fmaf(z2, -0.0117212f, 0.0526533f);
  p = fmaf(z2, p, -0.1164329f);
  p = fmaf(z2, p, 0.1935435f);
  p = fmaf(z2, p, -0.3326235f);
  p = fmaf(z2, p, 0.9999773f);
  float r = z * p;
  r = big ? 1.57079632679f - r : r;
  return copysignf(r, x);
}

__device__ inline float ciou_f(float b1x1,float b1y1,float b1x2,float b1y2,
                               float b2x1,float b2y1,float b2x2,float b2y2){
  const float eps = 1e-7f;
  float w1 = b1x2 - b1x1, h1 = b1y2 - b1y1 + eps;
  float w2 = b2x2 - b2x1, h2 = b2y2 - b2y1 + eps;
  float iw = fmaxf(fminf(b1x2, b2x2) - fmaxf(b1x1, b2x1), 0.f);
  float ih = fmaxf(fminf(b1y2, b2y2) - fmaxf(b1y1, b2y1), 0.f);
  float inter = iw * ih;
  float uni = w1 * h1 + w2 * h2 - inter + eps;
  float iou = inter * frcp(uni);
  float cw = fmaxf(b1x2, b2x2) - fminf(b1x1, b2x1);
  float ch = fmaxf(b1y2, b2y2) - fminf(b1y1, b2y1);
  float c2 = cw * cw + ch * ch + eps;
  float dx = b2x1 + b2x2 - b1x1 - b1x2;
  float dy = b2y1 + b2y2 - b1y1 - b1y2;
  float rho2 = (dx * dx + dy * dy) * 0.25f;
  float r1 = w1 * frcp(h1), r2 = w2 * frcp(h2);
  float dat = fast_atan((r2 - r1) * frcp(fmaf(r1, r2, 1.f)));
  float v = VCOEF * dat * dat;
  float alpha = v * frcp(v - iou + (1.0f + eps));
  return iou - (rho2 * frcp(c2) + v * alpha);
}

__device__ inline unsigned long long shfl_xor_u64(unsigned long long v, int mask){
  int lo = __shfl_xor((int)(unsigned)(v & 0xFFFFFFFFull), mask);
  int hi = __shfl_xor((int)(unsigned)(v >> 32), mask);
  return ((unsigned long long)(unsigned)hi << 32) | (unsigned)lo;
}

__device__ inline float softplus4(float4 v){
  float s = fmaxf(v.x, 0.f) + __logf(1.f + __expf(-fabsf(v.x)));
  s += fmaxf(v.y, 0.f) + __logf(1.f + __expf(-fabsf(v.y)));
  s += fmaxf(v.z, 0.f) + __logf(1.f + __expf(-fabsf(v.z)));
  s += fmaxf(v.w, 0.f) + __logf(1.f + __expf(-fabsf(v.w)));
  return s;
}

// ---------------- fused feature tile (unchanged from round 7) ----------------
template<int NA, int HW, int W, int AOFF>
__device__ inline float feat_tile(const float* __restrict__ f, int b, int o0,
                                  float* __restrict__ sT,
                                  float4* __restrict__ pbox,
                                  float4* __restrict__ lse,
                                  unsigned* __restrict__ mpos){
  constexpr int NA4  = NA / 4;
  constexpr int NDF4 = 64 * NA4;        // DFL float4 count for this tile
  constexpr int NIT  = NDF4 / 256;      // exact (16 / 4 / 9)
  int tid = threadIdx.x;
  const float* base = f + (size_t)b * NOC * HW + o0;

  {
    float4 x[NIT];
#pragma unroll
    for (int k = 0; k < NIT; k++){
      int idx = k * 256 + tid;
      int ch = idx / NA4, pos = idx - ch * NA4;
      x[k] = *(const float4*)(base + (size_t)ch * HW + pos * 4);
    }
#pragma unroll
    for (int k = 0; k < NIT; k++){
      int idx = k * 256 + tid;
      int ch = idx / NA4, pos = idx - ch * NA4;
      *(float4*)(&sT[ch * NA + pos * 4]) = x[k];
    }
  }
  __syncthreads();

  if (tid < NA){
    float d[4], ls[4];
#pragma unroll
    for (int s = 0; s < 4; s++){
      float xs[16];
#pragma unroll
      for (int j = 0; j < 16; j++) xs[j] = sT[(s * 16 + j) * NA + tid];
      float mx = xs[0];
#pragma unroll
      for (int j = 1; j < 16; j++) mx = fmaxf(mx, xs[j]);
      float sm = 0.f, dt = 0.f;
#pragma unroll
      for (int j = 0; j < 16; j++){
        float e = __expf(xs[j] - mx);
        sm += e; dt = fmaf(e, (float)j, dt);
      }
      d[s]  = dt * frcp(sm);
      ls[s] = mx + __logf(sm);
    }
    int o = o0 + tid;
    int iy = o / W;
    float ax = (float)(o - iy * W) + 0.5f;
    float ay = (float)iy + 0.5f;
    int gi = b * AT + AOFF + o;
    pbox[gi] = make_float4(ax - d[0], ay - d[1], ax + d[2], ay + d[3]);
    lse[gi]  = make_float4(ls[0], ls[1], ls[2], ls[3]);
    mpos[gi] = 0u;
  }

  // ---- class channels: linear float4 stream + softplus ----
  const float* cbase = base + (size_t)(4 * RM) * HW;
  constexpr int NCF4 = 80 * NA4;
  constexpr int NKC  = NCF4 / 256;
  float sp = 0.f;
#pragma unroll
  for (int k = 0; k < NKC; k++){
    int idx = k * 256 + tid;
    int ch = idx / NA4, pos = idx - ch * NA4;
    sp += softplus4(*(const float4*)(cbase + (size_t)ch * HW + pos * 4));
  }
  if constexpr (NCF4 % 256 != 0){
    int idx = NKC * 256 + tid;
    if (idx < NCF4){
      int ch = idx / NA4, pos = idx - ch * NA4;
      sp += softplus4(*(const float4*)(cbase + (size_t)ch * HW + pos * 4));
    }
  }
  return sp;
}

__global__ __launch_bounds__(256) void k_feat6(
    const float* __restrict__ f0, const float* __restrict__ f1,
    const float* __restrict__ f2, const float* __restrict__ tgt,
    float4* __restrict__ pbox, float4* __restrict__ lse,
    unsigned* __restrict__ mpos, double* __restrict__ bce_part,
    float* __restrict__ out5, float* __restrict__ gtbox,
    int* __restrict__ gtlab, float* __restrict__ gtmask,
    int* __restrict__ pa_i, int* __restrict__ po_i,
    int* __restrict__ topk_arr, int* __restrict__ bar){
  __shared__ float sT[64 * 256];   // 64 KB staging
  __shared__ float red[4];
  int blk = blockIdx.x;
  int tid = threadIdx.x;
  if (blk < NTILES){
    int b = blk / TPI, tt = blk - b * TPI;
    float sp;
    if (tt < 25)       sp = feat_tile<256, 6400, 80, 0>   (f0, b, tt * 256,        sT, pbox, lse, mpos);
    else if (tt < 31)  sp = feat_tile<256, 1600, 40, 6400>(f1, b, (tt - 25) * 256, sT, pbox, lse, mpos);
    else if (tt == 31) sp = feat_tile< 64, 1600, 40, 6400>(f1, b, 1536,            sT, pbox, lse, mpos);
    else if (tt == 32) sp = feat_tile<256,  400, 20, 8000>(f2, b, 0,               sT, pbox, lse, mpos);
    else               sp = feat_tile<144,  400, 20, 8000>(f2, b, 256,             sT, pbox, lse, mpos);
    for (int off = 32; off; off >>= 1) sp += __shfl_down(sp, off);
    int wid = tid >> 6, lid = tid & 63;
    if (lid == 0) red[wid] = sp;
    __syncthreads();
    if (tid == 0) bce_part[blk] = (double)(red[0] + red[1] + red[2] + red[3]);
  } else {
    // ---- prep block: targets preprocessing + buffer/barrier init ----
    for (int i = tid; i < BM * 5; i += 256) out5[i] = 0.f;
    for (int i = tid; i < MAXPOS; i += 256) topk_arr[i] = -1;
    for (int i = tid; i < BM; i += 256){ pa_i[i] = 0; po_i[i] = 0; }
    if (tid < 8) bar[tid] = 0;   // zero grid-barrier counters (pre-poisoned ws!)
    __syncthreads();
    for (int t = tid; t < BM; t += 256){
      int img = (int)tgt[t * 6 + 0];
      int j = t;
      while (j > 0 && (int)tgt[(j - 1) * 6 + 0] == img) j--;
      int pos = t - j;
      if (img >= 0 && img < BB && pos < MM){
        for (int k = 0; k < 5; k++)
          out5[(img * MM + pos) * 5 + k] = tgt[t * 6 + 1 + k];
      }
    }
    __syncthreads();
    for (int t = tid; t < BM; t += 256){
      float lab = out5[t * 5 + 0];
      float cx = out5[t * 5 + 1] * 640.f;
      float cy = out5[t * 5 + 2] * 640.f;
      float w  = out5[t * 5 + 3] * 640.f;
      float h  = out5[t * 5 + 4] * 640.f;
      float x1 = cx - w * 0.5f, y1 = cy - h * 0.5f;
      float x2 = cx + w * 0.5f, y2 = cy + h * 0.5f;
      gtbox[t * 4 + 0] = x1; gtbox[t * 4 + 1] = y1;
      gtbox[t * 4 + 2] = x2; gtbox[t * 4 + 3] = y2;
      gtlab[t] = (int)lab;
      gtmask[t] = ((x1 + y1 + x2 + y2) > 0.f) ? 1.f : 0.f;
    }
  }
}

// software grid barrier: safe because grid (640) <= guaranteed-resident
// blocks (4/CU x 256 CU = 1024, forced by __launch_bounds__(256,4); LDS
// 10.4KB/block -> 41.6KB/CU of 160KB). Counters zeroed by k_feat6's prep
// block, which stream-order precedes this kernel every iteration.
__device__ inline void grid_barrier(int* bar, int phase, int nblk){
  __syncthreads();
  if (threadIdx.x == 0){
    __threadfence();
    atomicAdd(&bar[phase], 1);
    while (__hip_atomic_load(&bar[phase], __ATOMIC_ACQUIRE,
                             __HIP_MEMORY_SCOPE_AGENT) < nblk){
      __builtin_amdgcn_s_sleep(8);
    }
    __threadfence();
  }
  __syncthreads();
}

// ---------------- fused tail: align + resolve + final + out ----------------
__global__ __launch_bounds__(256, 4) void k_tail(
    const float* __restrict__ f0, const float* __restrict__ f1,
    const float* __restrict__ f2, const float4* __restrict__ pbox,
    const float4* __restrict__ lse,
    const float* __restrict__ gtbox, const int* __restrict__ gtlab,
    const float* __restrict__ gtmask,
    unsigned* __restrict__ mpos, int* __restrict__ topk_arr,
    int* __restrict__ pa_i, int* __restrict__ po_i,
    const double* __restrict__ bce_part, float* __restrict__ fpart,
    int* __restrict__ bar, float* __restrict__ out){
  __shared__ float s_val[NSLOT];
  __shared__ int   s_anc[NSLOT];
  __shared__ unsigned long long s_red[4];
  __shared__ int   s_win[TK];
  __shared__ double sd[256];
  __shared__ double res[5];

  int pair = blockIdx.x;               // 0..BM-1
  int b = pair / MM, m = pair % MM;
  int tid = threadIdx.x;

  // ================= phase A: per-gt top-k alignment =================
  if (gtmask[pair] > 0.f){
    float gx1 = gtbox[pair * 4 + 0], gy1 = gtbox[pair * 4 + 1];
    float gx2 = gtbox[pair * 4 + 2], gy2 = gtbox[pair * 4 + 3];
    int lab = gtlab[pair];
    int base = 0;

#define PROC_LEVEL(FPTR, W, HW, AOFF, S)                                      \
  {                                                                           \
    const float s_ = (S); const float inv_ = 1.f / (S);                       \
    int x0 = max(0, (int)floorf(gx1 * inv_ - 0.5f));                          \
    int x1 = min((W) - 1, (int)ceilf(gx2 * inv_ - 0.5f));                     \
    int y0 = max(0, (int)floorf(gy1 * inv_ - 0.5f));                          \
    int y1 = min((W) - 1, (int)ceilf(gy2 * inv_ - 0.5f));                     \
    int nxx = x1 - x0 + 1, nyy = y1 - y0 + 1;                                 \
    if (nxx > 0 && nyy > 0){                                                  \
      int ntot = nxx * nyy;                                                   \
      unsigned magic = 0xFFFFFFFFu / (unsigned)nxx + 1u;                      \
      const float* clsrow = (FPTR) + (size_t)b * NOC * (HW)                   \
                            + (size_t)(4 * RM + lab) * (HW);                  \
      for (int t = tid; t < ntot; t += 256){                                  \
        int slot = base + t;                                                  \
        if (slot >= NSLOT) break;                                             \
        int iy = (int)(((unsigned long long)(unsigned)t * magic) >> 32);      \
        int ix = t - iy * nxx + x0;                                           \
        iy += y0;                                                             \
        float ax = ((float)ix + 0.5f) * s_;                                   \
        float ay = ((float)iy + 0.5f) * s_;                                   \
        float mn = fminf(fminf(ax - gx1, ay - gy1),                           \
                         fminf(gx2 - ax, gy2 - ay));                          \
        int o = iy * (W) + ix;                                                \
        int a = (AOFF) + o;                                                   \
        float aln = -1.f;                                                     \
        if (mn > EPS_A){                                                      \
          float4 pb = pbox[b * AT + a];                                       \
          float c = ciou_f(gx1, gy1, gx2, gy2,                                \
                           pb.x * s_, pb.y * s_, pb.z * s_, pb.w * s_);       \
          float ovl = fmaxf(c, 0.f);                                          \
          if (ovl > 0.f){                                                     \
            float xv = clsrow[o];                                             \
            float sc = frcp(1.f + __expf(-xv));                               \
            float o2 = ovl * ovl;                                             \
            aln = sqrtf(sc) * (o2 * o2 * o2);                                 \
          }                                                                   \
        }                                                                     \
        s_val[slot] = aln;                                                    \
        s_anc[slot] = a;                                                      \
      }                                                                       \
      base += ntot;                                                           \
    }                                                                         \
  }

    PROC_LEVEL(f0, 80, 6400, 0, 8.f)
    PROC_LEVEL(f1, 40, 1600, 6400, 16.f)
    PROC_LEVEL(f2, 20, 400, 8000, 32.f)
#undef PROC_LEVEL

    __syncthreads();
    int total = min(base, NSLOT);
    int wid = tid >> 6, lid = tid & 63;
    for (int r = 0; r < TK; r++){
      unsigned long long key = 0ULL;
      for (int i = tid; i < total; i += 256){
        float v = s_val[i];
        if (v > 0.f){
          unsigned long long k2 =
              ((unsigned long long)__float_as_uint(v) << 32) |
              (unsigned long long)(0xFFFFFFFFu - (unsigned)i);
          key = key > k2 ? key : k2;
        }
      }
      for (int xm = 1; xm < 64; xm <<= 1){
        unsigned long long o = shfl_xor_u64(key, xm);
        key = key > o ? key : o;
      }
      if (lid == 0) s_red[wid] = key;
      __syncthreads();
      if (tid == 0){
        unsigned long long k = s_red[0];
        k = k > s_red[1] ? k : s_red[1];
        k = k > s_red[2] ? k : s_red[2];
        k = k > s_red[3] ? k : s_red[3];
        if (k){
          int slot = (int)(0xFFFFFFFFu - (unsigned)(k & 0xFFFFFFFFull));
          s_win[r] = s_anc[slot];
          s_val[slot] = -1.f;
        } else s_win[r] = -1;
      }
      __syncthreads();
    }
    if (tid < TK){
      int a = s_win[tid];
      topk_arr[pair * TK + tid] = a;
      if (a >= 0) atomicOr(&mpos[(size_t)b * AT + a], 1u << m);
    }
  }
  grid_barrier(bar, 0, BM);

  // ================= phase B: resolve multi-claims (results stay in regs) ===
  bool owner = false;
  int a_own = -1, mr = 0;
  float aln_own = 0.f;
  if (tid < TK){
    int i = pair * TK + tid;
    int a = topk_arr[i];
    if (a >= 0){
      unsigned bits = mpos[(size_t)b * AT + a];
      if (m == __ffs(bits) - 1){
        owner = true; a_own = a;
        Lvl L = level_of(a, f0, f1, f2);
        float ax = ((float)(L.o % L.w) + 0.5f) * L.s;
        float ay = ((float)(L.o / L.w) + 0.5f) * L.s;
        float4 pb = pbox[b * AT + a];
        float px1 = pb.x * L.s, py1 = pb.y * L.s, px2 = pb.z * L.s, py2 = pb.w * L.s;
        float ovl;
        if (__popc(bits) > 1){
          float best = -1.f; int bm = 0;
          for (int mm = 0; mm < MM; mm++){
            float v = 0.f;
            if (gtmask[b * MM + mm] > 0.f){
              float x1 = gtbox[(b * MM + mm) * 4 + 0], y1 = gtbox[(b * MM + mm) * 4 + 1];
              float x2 = gtbox[(b * MM + mm) * 4 + 2], y2 = gtbox[(b * MM + mm) * 4 + 3];
              float mn = fminf(fminf(ax - x1, ay - y1), fminf(x2 - ax, y2 - ay));
              if (mn > EPS_A)
                v = fmaxf(ciou_f(x1, y1, x2, y2, px1, py1, px2, py2), 0.f);
            }
            if (v > best){ best = v; bm = mm; }
          }
          mr = bm; ovl = fmaxf(best, 0.f);
        } else {
          mr = m;
          float x1 = gtbox[(b * MM + mr) * 4 + 0], y1 = gtbox[(b * MM + mr) * 4 + 1];
          float x2 = gtbox[(b * MM + mr) * 4 + 2], y2 = gtbox[(b * MM + mr) * 4 + 3];
          ovl = fmaxf(ciou_f(x1, y1, x2, y2, px1, py1, px2, py2), 0.f);
        }
        int lab = gtlab[b * MM + mr];
        float xv = L.f[(size_t)b * NOC * L.hw + (size_t)(4 * RM + lab) * L.hw + L.o];
        float sc = frcp(1.f + __expf(-xv));
        float o2 = ovl * ovl;
        aln_own = sqrtf(sc) * (o2 * o2 * o2);
        atomicMax(&pa_i[b * MM + mr], __float_as_int(aln_own));
        atomicMax(&po_i[b * MM + mr], __float_as_int(ovl));
      }
    }
  }
  grid_barrier(bar, 1, BM);

  // ================= phase C: per-positive losses -> per-pair partials ======
  {
    float w_ = 0.f, clsp = 0.f, boxp = 0.f, dflp = 0.f;
    if (owner){
      int a = a_own;
      float pa = __int_as_float(pa_i[b * MM + mr]);
      float po = __int_as_float(po_i[b * MM + mr]);
      w_ = aln_own * po * frcp(pa + EPS_A);
      Lvl L = level_of(a, f0, f1, f2);
      const float* base2 = L.f + (size_t)b * NOC * L.hw + L.o;
      float ax = (float)(L.o % L.w) + 0.5f;
      float ay = (float)(L.o / L.w) + 0.5f;
      float inv_s = frcp(L.s);
      float tx1 = gtbox[(b * MM + mr) * 4 + 0] * inv_s, ty1 = gtbox[(b * MM + mr) * 4 + 1] * inv_s;
      float tx2 = gtbox[(b * MM + mr) * 4 + 2] * inv_s, ty2 = gtbox[(b * MM + mr) * 4 + 3] * inv_s;
      float4 pb = pbox[b * AT + a];
      float iou = ciou_f(pb.x, pb.y, pb.z, pb.w, tx1, ty1, tx2, ty2);
      boxp = (1.f - iou) * w_;
      float4 L4 = lse[b * AT + a];
      float lsv[4] = { L4.x, L4.y, L4.z, L4.w };
      float tv[4] = { ax - tx1, ay - ty1, tx2 - ax, ty2 - ay };
      float dfl = 0.f;
#pragma unroll
      for (int s4 = 0; s4 < 4; s4++){
        float t = fminf(fmaxf(tv[s4], 0.f), (float)(RM - 1) - 0.01f);
        int tl = (int)t;
        float wl = (float)(tl + 1) - t;
        float xl = base2[(size_t)(s4 * RM + tl) * L.hw];
        float xr = base2[(size_t)(s4 * RM + tl + 1) * L.hw];
        dfl += (lsv[s4] - xl) * wl + (lsv[s4] - xr) * (1.f - wl);
      }
      dflp = dfl * 0.25f * w_;
      int lab = gtlab[b * MM + mr];
      clsp = base2[(size_t)(4 * RM + lab) * L.hw] * w_;
    }
    // owner values live in lanes 0..9 of wave 0; full-wave shuffle reduce
    for (int off = 32; off; off >>= 1){
      w_   += __shfl_down(w_, off);
      clsp += __shfl_down(clsp, off);
      boxp += __shfl_down(boxp, off);
      dflp += __shfl_down(dflp, off);
    }
    if (tid == 0)
      *(float4*)(&fpart[pair * 4]) = make_float4(w_, clsp, boxp, dflp);
  }
  grid_barrier(bar, 2, BM);

  // ================= phase D: final reduction + output (block 0) =================
  if (blockIdx.x == 0){
    double part[5] = {0.0, 0.0, 0.0, 0.0, 0.0};
    for (int i = tid; i < BM; i += 256){
      float4 v = *(const float4*)(&fpart[i * 4]);
      part[0] += (double)v.x; part[1] += (double)v.y;
      part[2] += (double)v.z; part[3] += (double)v.w;
    }
    for (int i = tid; i < NTILES; i += 256) part[4] += bce_part[i];
#pragma unroll
    for (int j = 0; j < 5; j++){
      sd[tid] = part[j];
      __syncthreads();
      for (int off = 128; off; off >>= 1){
        if (tid < off) sd[tid] += sd[tid + off];
        __syncthreads();
      }
      if (tid == 0) res[j] = sd[0];
      __syncthreads();
    }
    if (tid == 0){
      double tss = res[0] > 1.0 ? res[0] : 1.0;
      double loss_box = res[2] / tss;
      double loss_cls = (res[4] - res[1]) / tss;
      double loss_dfl = res[3] / tss;
      float l0 = (float)(loss_box * 7.5);
      float l1 = (float)(loss_cls * 0.5);
      float l2 = (float)(loss_dfl * 1.5);
      out[0] = (l0 + l1 + l2) * 32.f;
      out[1] = l0;
      out[2] = l1;
      out[3] = l2;
    }
  }
}

extern "C" void kernel_launch(void* const* d_in, const int* in_sizes, int n_in,
                              void* d_out, int out_size, void* d_ws, size_t ws_size,
                              hipStream_t stream) {
  const float* f0 = (const float*)d_in[0];
  const float* f1 = (const float*)d_in[1];
  const float* f2 = (const float*)d_in[2];
  const float* tg = (const float*)d_in[3];
  float* out = (float*)d_out;

  char* w = (char*)d_ws;
  size_t off = 0;
  auto alloc = [&](size_t bytes) -> void* {
    void* p = w + off;
    off += (bytes + 255) & ~(size_t)255;
    return p;
  };
  float4*   pbox    = (float4*)  alloc((size_t)BA * 16);
  float4*   lse     = (float4*)  alloc((size_t)BA * 16);
  float*    gtbox   = (float*)   alloc((size_t)BM * 16);
  int*      gtlab   = (int*)     alloc((size_t)BM * 4);
  float*    gtmask  = (float*)   alloc((size_t)BM * 4);
  float*    out5    = (float*)   alloc((size_t)BM * 20);
  unsigned* mpos    = (unsigned*)alloc((size_t)BA * 4);     // zeroed by tile blocks
  int*      topk_arr= (int*)     alloc((size_t)MAXPOS * 4); // -1 by prep block
  int*      pa      = (int*)     alloc((size_t)BM * 4);
  int*      po      = (int*)     alloc((size_t)BM * 4);
  double*   bcep    = (double*)  alloc((size_t)NTILES * 8); // one partial per tile
  float*    fpart   = (float*)   alloc((size_t)BM * 16);    // per-pair loss partials
  int*      bar     = (int*)     alloc(8 * 4);              // grid-barrier counters

  k_feat6<<<NTILES + 1, 256, 0, stream>>>(f0, f1, f2, tg, pbox, lse, mpos, bcep,
                                          out5, gtbox, gtlab, gtmask, pa, po,
                                          topk_arr, bar);
  k_tail<<<BM, 256, 0, stream>>>(f0, f1, f2, pbox, lse, gtbox, gtlab, gtmask,
                                 mpos, topk_arr, pa, po, bcep, fpart, bar, out);
}

// Round 11
// 248.253 us; speedup vs baseline: 1.9051x; 1.9051x over previous
//
#include <hip/hip_runtime.h>
#include <math.h>

// ---- static config (mirrors reference) ----
constexpr int BB  = 32;     // batch
constexpr int MM  = 20;     // max gt per image
constexpr int NCC = 80;     // classes
constexpr int RM  = 16;     // reg_max
constexpr int NOC = 144;    // channels per head
constexpr int AT  = 8400;   // anchors
constexpr int TK  = 10;     // topk
constexpr int BA  = BB * AT;  // 268800
constexpr int BM  = BB * MM;  // 640
constexpr int MAXPOS = BM * TK; // 6400 topk entries
constexpr int NSLOT = 1024;     // max candidates per gt
constexpr float EPS_A = 1e-9f;
constexpr float VCOEF = 0.40528473456935108577551785283891f; // 4/pi^2

// fused feature pass: one block per (image, tile). Tiles per image:
// lvl0: 25x256 ; lvl1: 6x256 + 1x64 ; lvl2: 1x256 + 1x144  -> 34 tiles
constexpr int TPI    = 34;
constexpr int NTILES = BB * TPI;   // 1088
constexpr int NFIN   = MAXPOS / 256; // 25 blocks in k_final_out

// native clang vector for __builtin_nontemporal_load (HIP_vector_type is rejected)
typedef float f32x4 __attribute__((ext_vector_type(4)));

__device__ inline float4 ntload4(const float* p){
  f32x4 v = __builtin_nontemporal_load((const f32x4*)p);
  return make_float4(v.x, v.y, v.z, v.w);
}

struct Lvl { const float* f; int o, w, hw; float s; };

__device__ inline Lvl level_of(int a, const float* f0, const float* f1, const float* f2){
  Lvl L;
  if (a < 6400)      { L.f = f0; L.o = a;        L.w = 80; L.hw = 6400; L.s = 8.f;  }
  else if (a < 8000) { L.f = f1; L.o = a - 6400; L.w = 40; L.hw = 1600; L.s = 16.f; }
  else               { L.f = f2; L.o = a - 8000; L.w = 20; L.hw = 400;  L.s = 32.f; }
  return L;
}

__device__ inline float frcp(float x){ return __builtin_amdgcn_rcpf(x); }

// fast atan, |err| < ~2e-6
__device__ inline float fast_atan(float x){
  float ax = fabsf(x);
  bool big = ax > 1.f;
  float z = big ? frcp(ax) : ax;
  float z2 = z * z;
  float p = fmaf(z2, -0.0117212f, 0.0526533f);
  p = fmaf(z2, p, -0.1164329f);
  p = fmaf(z2, p, 0.1935435f);
  p = fmaf(z2, p, -0.3326235f);
  p = fmaf(z2, p, 0.9999773f);
  float r = z * p;
  r = big ? 1.57079632679f - r : r;
  return copysignf(r, x);
}

__device__ inline float ciou_f(float b1x1,float b1y1,float b1x2,float b1y2,
                               float b2x1,float b2y1,float b2x2,float b2y2){
  const float eps = 1e-7f;
  float w1 = b1x2 - b1x1, h1 = b1y2 - b1y1 + eps;
  float w2 = b2x2 - b2x1, h2 = b2y2 - b2y1 + eps;
  float iw = fmaxf(fminf(b1x2, b2x2) - fmaxf(b1x1, b2x1), 0.f);
  float ih = fmaxf(fminf(b1y2, b2y2) - fmaxf(b1y1, b2y1), 0.f);
  float inter = iw * ih;
  float uni = w1 * h1 + w2 * h2 - inter + eps;
  float iou = inter * frcp(uni);
  float cw = fmaxf(b1x2, b2x2) - fminf(b1x1, b2x1);
  float ch = fmaxf(b1y2, b2y2) - fminf(b1y1, b2y1);
  float c2 = cw * cw + ch * ch + eps;
  float dx = b2x1 + b2x2 - b1x1 - b1x2;
  float dy = b2y1 + b2y2 - b1y1 - b1y2;
  float rho2 = (dx * dx + dy * dy) * 0.25f;
  float r1 = w1 * frcp(h1), r2 = w2 * frcp(h2);
  float dat = fast_atan((r2 - r1) * frcp(fmaf(r1, r2, 1.f)));
  float v = VCOEF * dat * dat;
  float alpha = v * frcp(v - iou + (1.0f + eps));
  return iou - (rho2 * frcp(c2) + v * alpha);
}

__device__ inline unsigned long long shfl_xor_u64(unsigned long long v, int mask){
  int lo = __shfl_xor((int)(unsigned)(v & 0xFFFFFFFFull), mask);
  int hi = __shfl_xor((int)(unsigned)(v >> 32), mask);
  return ((unsigned long long)(unsigned)hi << 32) | (unsigned)lo;
}

__device__ inline float softplus4(float4 v){
  float s = fmaxf(v.x, 0.f) + __logf(1.f + __expf(-fabsf(v.x)));
  s += fmaxf(v.y, 0.f) + __logf(1.f + __expf(-fabsf(v.y)));
  s += fmaxf(v.z, 0.f) + __logf(1.f + __expf(-fabsf(v.z)));
  s += fmaxf(v.w, 0.f) + __logf(1.f + __expf(-fabsf(v.w)));
  return s;
}

// ---------------- fused feature tile (round 7 + non-temporal loads) ----------------
template<int NA, int HW, int W, int AOFF>
__device__ inline float feat_tile(const float* __restrict__ f, int b, int o0,
                                  float* __restrict__ sT,
                                  float4* __restrict__ pbox,
                                  float4* __restrict__ lse,
                                  unsigned* __restrict__ mpos){
  constexpr int NA4  = NA / 4;
  constexpr int NDF4 = 64 * NA4;        // DFL float4 count for this tile
  constexpr int NIT  = NDF4 / 256;      // exact (16 / 4 / 9)
  int tid = threadIdx.x;
  const float* base = f + (size_t)b * NOC * HW + o0;

  {
    float4 x[NIT];
#pragma unroll
    for (int k = 0; k < NIT; k++){
      int idx = k * 256 + tid;
      int ch = idx / NA4, pos = idx - ch * NA4;
      x[k] = ntload4(base + (size_t)ch * HW + pos * 4);
    }
#pragma unroll
    for (int k = 0; k < NIT; k++){
      int idx = k * 256 + tid;
      int ch = idx / NA4, pos = idx - ch * NA4;
      *(float4*)(&sT[ch * NA + pos * 4]) = x[k];
    }
  }
  __syncthreads();

  if (tid < NA){
    float d[4], ls[4];
#pragma unroll
    for (int s = 0; s < 4; s++){
      float xs[16];
#pragma unroll
      for (int j = 0; j < 16; j++) xs[j] = sT[(s * 16 + j) * NA + tid];
      float mx = xs[0];
#pragma unroll
      for (int j = 1; j < 16; j++) mx = fmaxf(mx, xs[j]);
      float sm = 0.f, dt = 0.f;
#pragma unroll
      for (int j = 0; j < 16; j++){
        float e = __expf(xs[j] - mx);
        sm += e; dt = fmaf(e, (float)j, dt);
      }
      d[s]  = dt * frcp(sm);
      ls[s] = mx + __logf(sm);
    }
    int o = o0 + tid;
    int iy = o / W;
    float ax = (float)(o - iy * W) + 0.5f;
    float ay = (float)iy + 0.5f;
    int gi = b * AT + AOFF + o;
    pbox[gi] = make_float4(ax - d[0], ay - d[1], ax + d[2], ay + d[3]);
    lse[gi]  = make_float4(ls[0], ls[1], ls[2], ls[3]);
    mpos[gi] = 0u;
  }

  // ---- class channels: linear float4 stream + softplus (non-temporal) ----
  const float* cbase = base + (size_t)(4 * RM) * HW;
  constexpr int NCF4 = 80 * NA4;
  constexpr int NKC  = NCF4 / 256;
  float sp = 0.f;
#pragma unroll
  for (int k = 0; k < NKC; k++){
    int idx = k * 256 + tid;
    int ch = idx / NA4, pos = idx - ch * NA4;
    sp += softplus4(ntload4(cbase + (size_t)ch * HW + pos * 4));
  }
  if constexpr (NCF4 % 256 != 0){
    int idx = NKC * 256 + tid;
    if (idx < NCF4){
      int ch = idx / NA4, pos = idx - ch * NA4;
      sp += softplus4(ntload4(cbase + (size_t)ch * HW + pos * 4));
    }
  }
  return sp;
}

__global__ __launch_bounds__(256) void k_feat6(
    const float* __restrict__ f0, const float* __restrict__ f1,
    const float* __restrict__ f2, const float* __restrict__ tgt,
    float4* __restrict__ pbox, float4* __restrict__ lse,
    unsigned* __restrict__ mpos, double* __restrict__ bce_part,
    float* __restrict__ out5, float* __restrict__ gtbox,
    int* __restrict__ gtlab, float* __restrict__ gtmask,
    int* __restrict__ pa_i, int* __restrict__ po_i,
    int* __restrict__ topk_arr, double* __restrict__ acc,
    int* __restrict__ donec){
  __shared__ float sT[64 * 256];   // 64 KB staging
  __shared__ float red[4];
  int blk = blockIdx.x;
  int tid = threadIdx.x;
  if (blk < NTILES){
    int b = blk / TPI, tt = blk - b * TPI;
    float sp;
    if (tt < 25)       sp = feat_tile<256, 6400, 80, 0>   (f0, b, tt * 256,        sT, pbox, lse, mpos);
    else if (tt < 31)  sp = feat_tile<256, 1600, 40, 6400>(f1, b, (tt - 25) * 256, sT, pbox, lse, mpos);
    else if (tt == 31) sp = feat_tile< 64, 1600, 40, 6400>(f1, b, 1536,            sT, pbox, lse, mpos);
    else if (tt == 32) sp = feat_tile<256,  400, 20, 8000>(f2, b, 0,               sT, pbox, lse, mpos);
    else               sp = feat_tile<144,  400, 20, 8000>(f2, b, 256,             sT, pbox, lse, mpos);
    for (int off = 32; off; off >>= 1) sp += __shfl_down(sp, off);
    int wid = tid >> 6, lid = tid & 63;
    if (lid == 0) red[wid] = sp;
    __syncthreads();
    if (tid == 0) bce_part[blk] = (double)(red[0] + red[1] + red[2] + red[3]);
  } else {
    // ---- prep block (targets preprocessing + buffer init), 256 threads ----
    for (int i = tid; i < BM * 5; i += 256) out5[i] = 0.f;
    for (int i = tid; i < MAXPOS; i += 256) topk_arr[i] = -1;
    for (int i = tid; i < BM; i += 256){ pa_i[i] = 0; po_i[i] = 0; }
    if (tid < 8) acc[tid] = 0.0;
    if (tid == 0) donec[0] = 0;
    __syncthreads();
    for (int t = tid; t < BM; t += 256){
      int img = (int)tgt[t * 6 + 0];
      int j = t;
      while (j > 0 && (int)tgt[(j - 1) * 6 + 0] == img) j--;
      int pos = t - j;
      if (img >= 0 && img < BB && pos < MM){
        for (int k = 0; k < 5; k++)
          out5[(img * MM + pos) * 5 + k] = tgt[t * 6 + 1 + k];
      }
    }
    __syncthreads();
    for (int t = tid; t < BM; t += 256){
      float lab = out5[t * 5 + 0];
      float cx = out5[t * 5 + 1] * 640.f;
      float cy = out5[t * 5 + 2] * 640.f;
      float w  = out5[t * 5 + 3] * 640.f;
      float h  = out5[t * 5 + 4] * 640.f;
      float x1 = cx - w * 0.5f, y1 = cy - h * 0.5f;
      float x2 = cx + w * 0.5f, y2 = cy + h * 0.5f;
      gtbox[t * 4 + 0] = x1; gtbox[t * 4 + 1] = y1;
      gtbox[t * 4 + 2] = x2; gtbox[t * 4 + 3] = y2;
      gtlab[t] = (int)lab;
      gtmask[t] = ((x1 + y1 + x2 + y2) > 0.f) ? 1.f : 0.f;
    }
  }
}

// ---------------- kernel 3: candidate LDS table + 10x block argmax ----------------
__global__ __launch_bounds__(256) void k_align(
    const float* __restrict__ f0, const float* __restrict__ f1,
    const float* __restrict__ f2, const float4* __restrict__ pbox,
    const float* __restrict__ gtbox, const int* __restrict__ gtlab,
    const float* __restrict__ gtmask,
    unsigned* __restrict__ mpos, int* __restrict__ topk_arr){
  int pair = blockIdx.x;
  int b = pair / MM, m = pair % MM;
  if (gtmask[pair] <= 0.f) return;  // topk_arr pre-inited to -1
  int tid = threadIdx.x;
  float gx1 = gtbox[pair * 4 + 0], gy1 = gtbox[pair * 4 + 1];
  float gx2 = gtbox[pair * 4 + 2], gy2 = gtbox[pair * 4 + 3];
  int lab = gtlab[pair];
  __shared__ float s_val[NSLOT];
  __shared__ int   s_anc[NSLOT];
  __shared__ unsigned long long s_red[4];
  __shared__ int   s_win[TK];
  int base = 0;

#define PROC_LEVEL(FPTR, W, HW, AOFF, S)                                      \
  {                                                                           \
    const float s_ = (S); const float inv_ = 1.f / (S);                       \
    int x0 = max(0, (int)floorf(gx1 * inv_ - 0.5f));                          \
    int x1 = min((W) - 1, (int)ceilf(gx2 * inv_ - 0.5f));                     \
    int y0 = max(0, (int)floorf(gy1 * inv_ - 0.5f));                          \
    int y1 = min((W) - 1, (int)ceilf(gy2 * inv_ - 0.5f));                     \
    int nxx = x1 - x0 + 1, nyy = y1 - y0 + 1;                                 \
    if (nxx > 0 && nyy > 0){                                                  \
      int ntot = nxx * nyy;                                                   \
      unsigned magic = 0xFFFFFFFFu / (unsigned)nxx + 1u;                      \
      const float* clsrow = (FPTR) + (size_t)b * NOC * (HW)                   \
                            + (size_t)(4 * RM + lab) * (HW);                  \
      for (int t = tid; t < ntot; t += 256){                                  \
        int slot = base + t;                                                  \
        if (slot >= NSLOT) break;                                             \
        int iy = (int)(((unsigned long long)(unsigned)t * magic) >> 32);      \
        int ix = t - iy * nxx + x0;                                           \
        iy += y0;                                                             \
        float ax = ((float)ix + 0.5f) * s_;                                   \
        float ay = ((float)iy + 0.5f) * s_;                                   \
        float mn = fminf(fminf(ax - gx1, ay - gy1),                           \
                         fminf(gx2 - ax, gy2 - ay));                          \
        int o = iy * (W) + ix;                                                \
        int a = (AOFF) + o;                                                   \
        float aln = -1.f;                                                     \
        if (mn > EPS_A){                                                      \
          float4 pb = pbox[b * AT + a];                                       \
          float c = ciou_f(gx1, gy1, gx2, gy2,                                \
                           pb.x * s_, pb.y * s_, pb.z * s_, pb.w * s_);       \
          float ovl = fmaxf(c, 0.f);                                          \
          if (ovl > 0.f){                                                     \
            float xv = clsrow[o];                                             \
            float sc = frcp(1.f + __expf(-xv));                               \
            float o2 = ovl * ovl;                                             \
            aln = sqrtf(sc) * (o2 * o2 * o2);                                 \
          }                                                                   \
        }                                                                     \
        s_val[slot] = aln;                                                    \
        s_anc[slot] = a;                                                      \
      }                                                                       \
      base += ntot;                                                           \
    }                                                                         \
  }

  PROC_LEVEL(f0, 80, 6400, 0, 8.f)
  PROC_LEVEL(f1, 40, 1600, 6400, 16.f)
  PROC_LEVEL(f2, 20, 400, 8000, 32.f)
#undef PROC_LEVEL

  __syncthreads();
  int total = min(base, NSLOT);
  int wid = tid >> 6, lid = tid & 63;
  for (int r = 0; r < TK; r++){
    unsigned long long key = 0ULL;
    for (int i = tid; i < total; i += 256){
      float v = s_val[i];
      if (v > 0.f){
        unsigned long long k2 =
            ((unsigned long long)__float_as_uint(v) << 32) |
            (unsigned long long)(0xFFFFFFFFu - (unsigned)i);
        key = key > k2 ? key : k2;
      }
    }
    for (int xm = 1; xm < 64; xm <<= 1){
      unsigned long long o = shfl_xor_u64(key, xm);
      key = key > o ? key : o;
    }
    if (lid == 0) s_red[wid] = key;
    __syncthreads();
    if (tid == 0){
      unsigned long long k = s_red[0];
      k = k > s_red[1] ? k : s_red[1];
      k = k > s_red[2] ? k : s_red[2];
      k = k > s_red[3] ? k : s_red[3];
      if (k){
        int slot = (int)(0xFFFFFFFFu - (unsigned)(k & 0xFFFFFFFFull));
        s_win[r] = s_anc[slot];
        s_val[slot] = -1.f;
      } else s_win[r] = -1;
    }
    __syncthreads();
  }
  if (tid < TK){
    int a = s_win[tid];
    topk_arr[pair * TK + tid] = a;
    if (a >= 0) atomicOr(&mpos[(size_t)b * AT + a], 1u << m);
  }
}

// ---------------- kernel 4: resolve multi-claims, pos maxima ----------------
__global__ __launch_bounds__(256) void k_resolve(
    const float* __restrict__ f0, const float* __restrict__ f1,
    const float* __restrict__ f2, const float4* __restrict__ pbox,
    const float* __restrict__ gtbox, const int* __restrict__ gtlab,
    const float* __restrict__ gtmask, const unsigned* __restrict__ mpos,
    const int* __restrict__ topk_arr,
    unsigned char* __restrict__ resm, float* __restrict__ resaln,
    int* __restrict__ pa_i, int* __restrict__ po_i){
  int i = blockIdx.x * 256 + threadIdx.x;  // 0..MAXPOS-1
  int a = topk_arr[i];
  if (a < 0) return;
  int pair = i / TK;
  int b = pair / MM, m = pair % MM;
  unsigned bits = mpos[(size_t)b * AT + a];
  if (m != __ffs(bits) - 1) return;        // one thread per positive anchor
  Lvl L = level_of(a, f0, f1, f2);
  float ax = ((float)(L.o % L.w) + 0.5f) * L.s;
  float ay = ((float)(L.o / L.w) + 0.5f) * L.s;
  float4 pb = pbox[b * AT + a];
  float px1 = pb.x * L.s, py1 = pb.y * L.s, px2 = pb.z * L.s, py2 = pb.w * L.s;
  int mr; float ovl;
  if (__popc(bits) > 1){
    float best = -1.f; int bm = 0;
    for (int mm = 0; mm < MM; mm++){
      float v = 0.f;
      if (gtmask[b * MM + mm] > 0.f){
        float x1 = gtbox[(b * MM + mm) * 4 + 0], y1 = gtbox[(b * MM + mm) * 4 + 1];
        float x2 = gtbox[(b * MM + mm) * 4 + 2], y2 = gtbox[(b * MM + mm) * 4 + 3];
        float mn = fminf(fminf(ax - x1, ay - y1), fminf(x2 - ax, y2 - ay));
        if (mn > EPS_A)
          v = fmaxf(ciou_f(x1, y1, x2, y2, px1, py1, px2, py2), 0.f);
      }
      if (v > best){ best = v; bm = mm; }
    }
    mr = bm; ovl = fmaxf(best, 0.f);
  } else {
    mr = m;
    float x1 = gtbox[(b * MM + mr) * 4 + 0], y1 = gtbox[(b * MM + mr) * 4 + 1];
    float x2 = gtbox[(b * MM + mr) * 4 + 2], y2 = gtbox[(b * MM + mr) * 4 + 3];
    ovl = fmaxf(ciou_f(x1, y1, x2, y2, px1, py1, px2, py2), 0.f);
  }
  int lab = gtlab[b * MM + mr];
  float xv = L.f[(size_t)b * NOC * L.hw + (size_t)(4 * RM + lab) * L.hw + L.o];
  float sc = frcp(1.f + __expf(-xv));
  float o2 = ovl * ovl;
  float aln = sqrtf(sc) * (o2 * o2 * o2);
  size_t gi = (size_t)b * AT + a;
  resm[gi] = (unsigned char)mr;
  resaln[gi] = aln;
  atomicMax(&pa_i[b * MM + mr], __float_as_int(aln));
  atomicMax(&po_i[b * MM + mr], __float_as_int(ovl));
}

// ---------------- kernel 5: per-positive losses + last-block finalize ----------------
__global__ __launch_bounds__(256) void k_final_out(
    const float* __restrict__ f0, const float* __restrict__ f1,
    const float* __restrict__ f2,
    const float4* __restrict__ pbox, const float4* __restrict__ lse,
    const float* __restrict__ gtbox, const int* __restrict__ gtlab,
    const int* __restrict__ pa_i, const int* __restrict__ po_i,
    const unsigned* __restrict__ mpos, const int* __restrict__ topk_arr,
    const unsigned char* __restrict__ resm, const float* __restrict__ resaln,
    double* __restrict__ acc, const double* __restrict__ bce_part,
    int* __restrict__ donec, float* __restrict__ out){
  int i = blockIdx.x * 256 + threadIdx.x;
  float w_ = 0.f, clsp = 0.f, boxp = 0.f, dflp = 0.f;
  int a = topk_arr[i];
  if (a >= 0){
    int pair = i / TK;
    int b = pair / MM, m = pair % MM;
    unsigned bits = mpos[(size_t)b * AT + a];
    if (m == __ffs(bits) - 1){
      size_t gi = (size_t)b * AT + a;
      int mr = (int)resm[gi];
      float aln = resaln[gi];
      float pa = __int_as_float(pa_i[b * MM + mr]);
      float po = __int_as_float(po_i[b * MM + mr]);
      w_ = aln * po * frcp(pa + EPS_A);
      Lvl L = level_of(a, f0, f1, f2);
      const float* base = L.f + (size_t)b * NOC * L.hw + L.o;
      float ax = (float)(L.o % L.w) + 0.5f;
      float ay = (float)(L.o / L.w) + 0.5f;
      float inv_s = frcp(L.s);
      float tx1 = gtbox[(b * MM + mr) * 4 + 0] * inv_s, ty1 = gtbox[(b * MM + mr) * 4 + 1] * inv_s;
      float tx2 = gtbox[(b * MM + mr) * 4 + 2] * inv_s, ty2 = gtbox[(b * MM + mr) * 4 + 3] * inv_s;
      float4 pb = pbox[b * AT + a];
      float iou = ciou_f(pb.x, pb.y, pb.z, pb.w, tx1, ty1, tx2, ty2);
      boxp = (1.f - iou) * w_;
      float4 L4 = lse[b * AT + a];
      float lsv[4] = { L4.x, L4.y, L4.z, L4.w };
      float tv[4] = { ax - tx1, ay - ty1, tx2 - ax, ty2 - ay };
      float dfl = 0.f;
#pragma unroll
      for (int s4 = 0; s4 < 4; s4++){
        float t = fminf(fmaxf(tv[s4], 0.f), (float)(RM - 1) - 0.01f);
        int tl = (int)t;
        float wl = (float)(tl + 1) - t;
        float xl = base[(size_t)(s4 * RM + tl) * L.hw];
        float xr = base[(size_t)(s4 * RM + tl + 1) * L.hw];
        dfl += (lsv[s4] - xl) * wl + (lsv[s4] - xr) * (1.f - wl);
      }
      dflp = dfl * 0.25f * w_;
      int lab = gtlab[b * MM + mr];
      clsp = base[(size_t)(4 * RM + lab) * L.hw] * w_;
    }
  }
  __shared__ float red[4][4];
  __shared__ double sd[256];
  float vals[4] = { w_, clsp, boxp, dflp };
  int wid = threadIdx.x >> 6, lid = threadIdx.x & 63;
#pragma unroll
  for (int j = 0; j < 4; j++){
    float v = vals[j];
    for (int off = 32; off; off >>= 1) v += __shfl_down(v, off);
    if (lid == 0) red[wid][j] = v;
  }
  __syncthreads();
  __shared__ bool s_last;
  if (threadIdx.x == 0){
    float t0 = 0.f, t1 = 0.f, t2 = 0.f, t3 = 0.f;
    for (int w2 = 0; w2 < 4; w2++){
      t0 += red[w2][0]; t1 += red[w2][1]; t2 += red[w2][2]; t3 += red[w2][3];
    }
    atomicAdd(&acc[0], (double)t0);
    atomicAdd(&acc[1], (double)t1);
    atomicAdd(&acc[2], (double)t2);
    atomicAdd(&acc[3], (double)t3);
    __threadfence();
    int prev = atomicAdd(donec, 1);
    s_last = (prev == NFIN - 1);
  }
  __syncthreads();
  if (!s_last) return;

  // ---- last block: reduce BCE partials + finalize output ----
  __threadfence();
  double s = 0.0;
  for (int k = threadIdx.x; k < NTILES; k += 256) s += bce_part[k];
  sd[threadIdx.x] = s;
  __syncthreads();
  for (int off = 128; off; off >>= 1){
    if (threadIdx.x < off) sd[threadIdx.x] += sd[threadIdx.x + off];
    __syncthreads();
  }
  if (threadIdx.x == 0){
    double bce_sum = sd[0];
    double a0 = acc[0], a1 = acc[1], a2 = acc[2], a3 = acc[3];
    double tss = a0 > 1.0 ? a0 : 1.0;
    double loss_box = a2 / tss;
    double loss_cls = (bce_sum - a1) / tss;
    double loss_dfl = a3 / tss;
    float l0 = (float)(loss_box * 7.5);
    float l1 = (float)(loss_cls * 0.5);
    float l2 = (float)(loss_dfl * 1.5);
    out[0] = (l0 + l1 + l2) * 32.f;
    out[1] = l0;
    out[2] = l1;
    out[3] = l2;
  }
}

extern "C" void kernel_launch(void* const* d_in, const int* in_sizes, int n_in,
                              void* d_out, int out_size, void* d_ws, size_t ws_size,
                              hipStream_t stream) {
  const float* f0 = (const float*)d_in[0];
  const float* f1 = (const float*)d_in[1];
  const float* f2 = (const float*)d_in[2];
  const float* tg = (const float*)d_in[3];
  float* out = (float*)d_out;

  char* w = (char*)d_ws;
  size_t off = 0;
  auto alloc = [&](size_t bytes) -> void* {
    void* p = w + off;
    off += (bytes + 255) & ~(size_t)255;
    return p;
  };
  float4*        pbox    = (float4*)       alloc((size_t)BA * 16);
  float4*        lse     = (float4*)       alloc((size_t)BA * 16);
  float*         gtbox   = (float*)        alloc((size_t)BM * 16);
  int*           gtlab   = (int*)          alloc((size_t)BM * 4);
  float*         gtmask  = (float*)        alloc((size_t)BM * 4);
  float*         out5    = (float*)        alloc((size_t)BM * 20);
  unsigned*      mpos    = (unsigned*)     alloc((size_t)BA * 4);  // zeroed by tile blocks
  int*           topk_arr= (int*)          alloc((size_t)MAXPOS * 4); // -1 by prep block
  unsigned char* resm    = (unsigned char*)alloc((size_t)BA);      // write-before-read
  float*         resaln  = (float*)        alloc((size_t)BA * 4);  // write-before-read
  int*           pa      = (int*)          alloc((size_t)BM * 4);
  int*           po      = (int*)          alloc((size_t)BM * 4);
  double*        acc     = (double*)       alloc(8 * 8);
  double*        bcep    = (double*)       alloc((size_t)NTILES * 8); // one partial per tile
  int*           donec   = (int*)          alloc(8 * 4);             // done counter (zeroed by prep)

  k_feat6<<<NTILES + 1, 256, 0, stream>>>(f0, f1, f2, tg, pbox, lse, mpos, bcep,
                                          out5, gtbox, gtlab, gtmask, pa, po,
                                          topk_arr, acc, donec);
  k_align<<<BM, 256, 0, stream>>>(f0, f1, f2, pbox, gtbox, gtlab, gtmask, mpos, topk_arr);
  k_resolve<<<MAXPOS / 256, 256, 0, stream>>>(f0, f1, f2, pbox, gtbox, gtlab, gtmask,
                                              mpos, topk_arr, resm, resaln, pa, po);
  k_final_out<<<NFIN, 256, 0, stream>>>(f0, f1, f2, pbox, lse, gtbox, gtlab,
                                        pa, po, mpos, topk_arr, resm, resaln,
                                        acc, bcep, donec, out);
}